// Round 8
// baseline (101.261 us; speedup 1.0000x reference)
//
#include <hip/hip_runtime.h>

// GCN layer: out = relu( segment_sum( (h@W * norm)[src], dst ) * norm + b )
//
// Pipeline:
//   K0 wconv        : Wtg = bf16(W) in MFMA B-fragment order; zero gcur[]
//   K1 gemm_and_bin : grid-fused, BIN BLOCKS FIRST for co-residency:
//                     blocks [0, nbinb)      : one-pass bin of 2048 edges by
//                       dst>>6 (reg-held edges, LDS rank, 1 global atomic per
//                       (block,bucket) reservation, packed emit)
//                     blocks [nbinb, +nrb)   : scaledh = bf16((h@W)*norm) MFMA
//   K2 bucket_reduce: per-bucket LDS counting sort, then group-owns-node
//                     gather (16 lanes/edge, uint2 = 4 bf16 ch/lane, A/B
//                     interleave -> 4 loads in flight), fused *norm+b, relu.

typedef unsigned int u32;
typedef unsigned short u16;
typedef __attribute__((ext_vector_type(8))) short s16x8;   // 8 bf16 = 4 VGPR
typedef __attribute__((ext_vector_type(4))) float f32x4;

#define NB_LOG 6
#define NPB 64             // nodes per bucket
#define CAP 2048           // edge capacity per bucket (mean ~1024, sd ~32)
#define MAXB 2048          // max buckets supported (N <= 131072)
#define EPB 2048           // edges per bin block (256 thr x 8)
#define RT 256             // bucket_reduce threads (4 waves)

__device__ __forceinline__ float bf2f(u16 v) {
  return __uint_as_float(((u32)v) << 16);
}
__device__ __forceinline__ u16 f2bf(float f) {
  u32 u = __float_as_uint(f);
  return (u16)((u + 0x7fffu + ((u >> 16) & 1u)) >> 16);  // RNE
}
__device__ __forceinline__ void acc_bf16x4(float4& a, uint2 v) {
  a.x += __uint_as_float(v.x << 16);
  a.y += __uint_as_float(v.x & 0xFFFF0000u);
  a.z += __uint_as_float(v.y << 16);
  a.w += __uint_as_float(v.y & 0xFFFF0000u);
}

// ---- K0: W -> bf16 in B-fragment order; zero gcur ----
__global__ __launch_bounds__(256) void wconv(
    const float* __restrict__ W, u16* __restrict__ Wtg, u32* __restrict__ gcur) {
  int o = blockIdx.x * 256 + threadIdx.x;  // 0..8191
  int j = o & 7, col = (o >> 3) & 15, kq = (o >> 7) & 3, ks = (o >> 9) & 3,
      ct = (o >> 11) & 3;
  int k = ks * 32 + kq * 8 + j;
  int n = ct * 16 + col;
  Wtg[o] = f2bf(W[k * 64 + n]);
  if (o < MAXB) gcur[o] = 0;
}

// ---- K1: fused edge binning (first) + MFMA GEMM ----
__global__ __launch_bounds__(256) void gemm_and_bin(
    const float* __restrict__ h, const float* __restrict__ norm,
    const u16* __restrict__ Wtg, u16* __restrict__ scaledh, int N, int nbinb,
    const int* __restrict__ src, const int* __restrict__ dst,
    u32* __restrict__ gcur, u32* __restrict__ bins, int E) {
  __shared__ u32 lhist[MAXB];  // 8 KB
  __shared__ u32 lbase[MAXB];  // 8 KB

  if ((int)blockIdx.x < nbinb) {
    // ---- bin path: one pass (reg edges -> LDS rank -> reserve -> emit) ----
    int t = threadIdx.x;
    for (int i = t; i < MAXB; i += 256) lhist[i] = 0;
    __syncthreads();
    int e0 = blockIdx.x * EPB;
    int s[8], d[8];
    u32 r[8];
#pragma unroll
    for (int k = 0; k < 8; ++k) {
      int e = e0 + k * 256 + t;  // coalesced
      bool ok = e < E;
      s[k] = ok ? src[e] : 0;
      d[k] = ok ? dst[e] : -1;
    }
#pragma unroll
    for (int k = 0; k < 8; ++k) {
      if (d[k] >= 0) r[k] = atomicAdd(&lhist[d[k] >> NB_LOG], 1u);  // ds_add_rtn
    }
    __syncthreads();
    for (int i = t; i < MAXB; i += 256) {
      u32 c = lhist[i];
      lbase[i] = c ? atomicAdd(&gcur[i], c) : 0u;  // 1 global atomic/(block,bucket)
    }
    __syncthreads();
#pragma unroll
    for (int k = 0; k < 8; ++k) {
      if (d[k] >= 0) {
        int bk = d[k] >> NB_LOG;
        u32 p = lbase[bk] + r[k];
        if (p < CAP)
          bins[(size_t)bk * CAP + p] = ((u32)s[k] << NB_LOG) | (u32)(d[k] & (NPB - 1));
      }
    }
    return;
  }

  // ---- GEMM path: 64 rows/block (4 waves x 16 rows), 64 cols ----
  int lane = threadIdx.x & 63, wid = threadIdx.x >> 6;
  int col = lane & 15, kq = lane >> 4;

  s16x8 bfrag[4][4];
#pragma unroll
  for (int ct = 0; ct < 4; ++ct)
#pragma unroll
    for (int ks = 0; ks < 4; ++ks) {
      int f = ct * 16 + ks * 4 + kq;
      bfrag[ct][ks] =
          *reinterpret_cast<const s16x8*>(Wtg + ((size_t)(f * 16 + col) * 8));
    }

  int row0 = ((int)blockIdx.x - nbinb) * 64 + wid * 16;
  int myrow = row0 + col;
  int ldrow = myrow < N ? myrow : (N - 1);
  const float* __restrict__ hrow = h + (size_t)ldrow * 128 + kq * 8;

  f32x4 acc[4];
#pragma unroll
  for (int ct = 0; ct < 4; ++ct) acc[ct] = (f32x4){0.f, 0.f, 0.f, 0.f};

#pragma unroll
  for (int ks = 0; ks < 4; ++ks) {
    float4 x0 = *reinterpret_cast<const float4*>(hrow + ks * 32);
    float4 x1 = *reinterpret_cast<const float4*>(hrow + ks * 32 + 4);
    s16x8 a;
    a[0] = (short)f2bf(x0.x); a[1] = (short)f2bf(x0.y);
    a[2] = (short)f2bf(x0.z); a[3] = (short)f2bf(x0.w);
    a[4] = (short)f2bf(x1.x); a[5] = (short)f2bf(x1.y);
    a[6] = (short)f2bf(x1.z); a[7] = (short)f2bf(x1.w);
#pragma unroll
    for (int ct = 0; ct < 4; ++ct)
      acc[ct] =
          __builtin_amdgcn_mfma_f32_16x16x32_bf16(a, bfrag[ct][ks], acc[ct], 0, 0, 0);
  }

#pragma unroll
  for (int reg = 0; reg < 4; ++reg) {
    int node = row0 + kq * 4 + reg;
    if (node < N) {
      float nm = norm[node];
#pragma unroll
      for (int ct = 0; ct < 4; ++ct)
        scaledh[(size_t)node * 64 + ct * 16 + col] = f2bf(acc[ct][reg] * nm);
    }
  }
}

// ---- K2: per-bucket counting sort + group-owns-node gather-reduce ----
__global__ __launch_bounds__(RT) void bucket_reduce(
    const u16* __restrict__ scaledh, const u32* __restrict__ bins,
    const u32* __restrict__ gcur, const float* __restrict__ norm,
    const float4* __restrict__ bias4, float* __restrict__ out, int N) {
  __shared__ u32 hist[NPB];
  __shared__ u32 startp[NPB + 1];
  __shared__ u32 sorted[CAP];
  int bkt = blockIdx.x;
  int t = threadIdx.x, lane = t & 63, wid = t >> 6;
  int cnt = (int)gcur[bkt];
  if (cnt > CAP) cnt = CAP;
  if (t < NPB) hist[t] = 0;
  __syncthreads();

  const u32* __restrict__ my = bins + (size_t)bkt * CAP;
  u32 w[CAP / RT];
  u32 rk[CAP / RT];
#pragma unroll
  for (int k = 0; k < CAP / RT; ++k) {
    int e = k * RT + t;  // coalesced
    w[k] = (e < cnt) ? my[e] : 0xFFFFFFFFu;
  }
#pragma unroll
  for (int k = 0; k < CAP / RT; ++k) {
    if (w[k] != 0xFFFFFFFFu)
      rk[k] = atomicAdd(&hist[w[k] & (NPB - 1)], 1u);  // native int LDS atomic
  }
  __syncthreads();
  // wave-level exclusive scan of hist[0..63] (wave 0)
  if (t < NPB) {
    u32 v = hist[t];
    u32 inc = v;
#pragma unroll
    for (int m = 1; m < NPB; m <<= 1) {
      u32 x = __shfl_up(inc, m);
      if (t >= m) inc += x;
    }
    startp[t] = inc - v;
    if (t == NPB - 1) startp[NPB] = inc;
  }
  __syncthreads();
#pragma unroll
  for (int k = 0; k < CAP / RT; ++k) {
    if (w[k] != 0xFFFFFFFFu)
      sorted[startp[w[k] & (NPB - 1)] + rk[k]] = w[k] >> NB_LOG;
  }
  __syncthreads();

  // Gather: 16-lane group owns one node; A/B interleave -> 4 loads in flight.
  int grp = lane >> 4, c4 = lane & 15;
  float4 bl = bias4[c4];
  int base = bkt << NB_LOG;
  int cm1 = cnt - 1;  // clamp for speculative LDS reads (loop empty if cnt==0)
#pragma unroll
  for (int round = 0; round < 2; ++round) {
    int rA = (wid << 4) + (round << 3) + grp;  // wave strip: 16 nodes
    int rB = rA + 4;
    int jA = (int)startp[rA], eA = (int)startp[rA + 1];
    int jB = (int)startp[rB], eB = (int)startp[rB + 1];
    float4 aA = make_float4(0.f, 0.f, 0.f, 0.f);
    float4 aB = make_float4(0.f, 0.f, 0.f, 0.f);
    while (jA < eA || jB < eB) {
      int iA0 = (int)sorted[min(jA, cm1)];
      int iA1 = (int)sorted[min(jA + 1, cm1)];
      int iB0 = (int)sorted[min(jB, cm1)];
      int iB1 = (int)sorted[min(jB + 1, cm1)];
      uint2 vA0 = *reinterpret_cast<const uint2*>(scaledh + ((size_t)iA0 << 6) + (c4 << 2));
      uint2 vA1 = *reinterpret_cast<const uint2*>(scaledh + ((size_t)iA1 << 6) + (c4 << 2));
      uint2 vB0 = *reinterpret_cast<const uint2*>(scaledh + ((size_t)iB0 << 6) + (c4 << 2));
      uint2 vB1 = *reinterpret_cast<const uint2*>(scaledh + ((size_t)iB1 << 6) + (c4 << 2));
      uint2 z = make_uint2(0u, 0u);
      vA0 = (jA < eA) ? vA0 : z;
      vA1 = (jA + 1 < eA) ? vA1 : z;
      vB0 = (jB < eB) ? vB0 : z;
      vB1 = (jB + 1 < eB) ? vB1 : z;
      acc_bf16x4(aA, vA0);
      acc_bf16x4(aA, vA1);
      acc_bf16x4(aB, vB0);
      acc_bf16x4(aB, vB1);
      jA += 2;
      jB += 2;
    }
    int nodeA = base + rA, nodeB = base + rB;
    if (nodeA < N) {
      float nm = norm[nodeA];
      float4 o;
      o.x = fmaxf(fmaf(aA.x, nm, bl.x), 0.f);
      o.y = fmaxf(fmaf(aA.y, nm, bl.y), 0.f);
      o.z = fmaxf(fmaf(aA.z, nm, bl.z), 0.f);
      o.w = fmaxf(fmaf(aA.w, nm, bl.w), 0.f);
      *reinterpret_cast<float4*>(out + (size_t)nodeA * 64 + (c4 << 2)) = o;
    }
    if (nodeB < N) {
      float nm = norm[nodeB];
      float4 o;
      o.x = fmaxf(fmaf(aB.x, nm, bl.x), 0.f);
      o.y = fmaxf(fmaf(aB.y, nm, bl.y), 0.f);
      o.z = fmaxf(fmaf(aB.z, nm, bl.z), 0.f);
      o.w = fmaxf(fmaf(aB.w, nm, bl.w), 0.f);
      *reinterpret_cast<float4*>(out + (size_t)nodeB * 64 + (c4 << 2)) = o;
    }
  }
}

// ---- fallback (atomic scatter) ----
__global__ __launch_bounds__(256) void zero_out(float4* __restrict__ o4, size_t n4) {
  size_t tid = blockIdx.x * 256 + threadIdx.x;
  size_t stride = (size_t)gridDim.x * 256;
  for (size_t i = tid; i < n4; i += stride) o4[i] = make_float4(0.f, 0.f, 0.f, 0.f);
}

__global__ __launch_bounds__(256) void scatter_edges(
    const u16* __restrict__ scaledh, const int* __restrict__ src,
    const int* __restrict__ dst, float* __restrict__ agg, int E) {
  int lane = threadIdx.x & 63;
  int gwid = (blockIdx.x * 256 + threadIdx.x) >> 6;
  int nw = (gridDim.x * 256) >> 6;
  for (int e = gwid; e < E; e += nw) {
    int s = __builtin_amdgcn_readfirstlane(src[e]);
    int d = __builtin_amdgcn_readfirstlane(dst[e]);
    float v = bf2f(scaledh[(size_t)s * 64 + lane]);
    unsafeAtomicAdd(&agg[(size_t)d * 64 + lane], v);
  }
}

__global__ __launch_bounds__(256) void finalize(
    float4* __restrict__ out4, const float* __restrict__ norm,
    const float4* __restrict__ b4, int N) {
  size_t total4 = (size_t)N * 16;
  size_t tid = blockIdx.x * 256 + threadIdx.x;
  size_t stride = (size_t)gridDim.x * 256;
  for (size_t t = tid; t < total4; t += stride) {
    int i = (int)(t >> 4), q = (int)(t & 15);
    float4 v = out4[t];
    float nm = norm[i];
    float4 bb = b4[q];
    v.x = fmaxf(fmaf(v.x, nm, bb.x), 0.f);
    v.y = fmaxf(fmaf(v.y, nm, bb.y), 0.f);
    v.z = fmaxf(fmaf(v.z, nm, bb.z), 0.f);
    v.w = fmaxf(fmaf(v.w, nm, bb.w), 0.f);
    out4[t] = v;
  }
}

extern "C" void kernel_launch(void* const* d_in, const int* in_sizes, int n_in,
                              void* d_out, int out_size, void* d_ws, size_t ws_size,
                              hipStream_t stream) {
  const float* h    = (const float*)d_in[0];
  const float* norm = (const float*)d_in[1];
  const float* W    = (const float*)d_in[2];
  const float* b    = (const float*)d_in[3];
  const int*   src  = (const int*)d_in[4];
  const int*   dst  = (const int*)d_in[5];

  int N = in_sizes[1];
  int E = in_sizes[4];
  int nbuckets = (N + NPB - 1) >> NB_LOG;
  int nrb = (N + 63) >> 6;
  int nbinb = (E + EPB - 1) / EPB;

  char* ws = (char*)d_ws;
  size_t off = 0;
  u16* scaledh = (u16*)(ws + off); off += (((size_t)N * 64 * 2) + 255) & ~(size_t)255;
  u32* gcur    = (u32*)(ws + off); off += (MAXB * 4 + 255) & ~(size_t)255;
  u16* Wtg     = (u16*)(ws + off); off += (8192 * 2 + 255) & ~(size_t)255;
  u32* bins    = (u32*)(ws + off); off += (size_t)MAXB * CAP * 4;
  size_t needed = off;
  size_t needed_fb = (size_t)((char*)bins - ws);  // fallback: scaledh+gcur+Wtg only

  if (ws_size >= needed && nbuckets <= MAXB) {
    wconv<<<32, 256, 0, stream>>>(W, Wtg, gcur);
    gemm_and_bin<<<nbinb + nrb, 256, 0, stream>>>(h, norm, Wtg, scaledh, N, nbinb,
                                                  src, dst, gcur, bins, E);
    bucket_reduce<<<nbuckets, RT, 0, stream>>>(scaledh, bins, gcur, norm,
                                               (const float4*)b, (float*)d_out, N);
  } else if (ws_size >= needed_fb) {
    float* agg = (float*)d_out;
    wconv<<<32, 256, 0, stream>>>(W, Wtg, gcur);
    gemm_and_bin<<<nrb, 256, 0, stream>>>(h, norm, Wtg, scaledh, N, 0,
                                          src, dst, gcur, bins, E);
    zero_out<<<1024, 256, 0, stream>>>((float4*)agg, (size_t)N * 16);
    scatter_edges<<<2048, 256, 0, stream>>>(scaledh, src, dst, agg, E);
    finalize<<<1024, 256, 0, stream>>>((float4*)agg, norm, (const float4*)b, N);
  }
}

// Round 10
// 80.065 us; speedup vs baseline: 1.2647x; 1.2647x over previous
//
#include <hip/hip_runtime.h>

// GCN layer: out = relu( segment_sum( (h@W * norm)[src], dst ) * norm + b )
//
// Pipeline (de-fused; each stage is the best measured variant):
//   K0 wconv        : Wtg = bf16(W) in MFMA B-fragment order; zero gcur[]  (~2us)
//   K1 gemm_mfma    : scaledh = bf16((h@W)*norm) via mfma_f32_16x16x32_bf16 (~15us)
//   K2 bin_edges    : bin edges by dst>>6, 1024 thr x 8 edges; LDS rank +
//                     1 global atomic per (block,bucket) reservation (~17us)
//   K3 bucket_reduce: per-bucket LDS counting sort + group-owns-node gather
//                     (16 lanes/edge, uint2 loads, A/B interleave), fused
//                     *norm+b, relu float4 store (~8us)

typedef unsigned int u32;
typedef unsigned short u16;
typedef __attribute__((ext_vector_type(8))) short s16x8;   // 8 bf16 = 4 VGPR
typedef __attribute__((ext_vector_type(4))) float f32x4;

#define NB_LOG 6
#define NPB 64             // nodes per bucket
#define CAP 2048           // edge capacity per bucket (mean ~1024, sd ~32)
#define MAXB 2048          // max buckets supported (N <= 131072)
#define EPB 8192           // edges per bin block (1024 thr x 8)
#define RT 256             // bucket_reduce threads (4 waves)

__device__ __forceinline__ float bf2f(u16 v) {
  return __uint_as_float(((u32)v) << 16);
}
__device__ __forceinline__ u16 f2bf(float f) {
  u32 u = __float_as_uint(f);
  return (u16)((u + 0x7fffu + ((u >> 16) & 1u)) >> 16);  // RNE
}
__device__ __forceinline__ void acc_bf16x4(float4& a, uint2 v) {
  a.x += __uint_as_float(v.x << 16);
  a.y += __uint_as_float(v.x & 0xFFFF0000u);
  a.z += __uint_as_float(v.y << 16);
  a.w += __uint_as_float(v.y & 0xFFFF0000u);
}

// ---- K0: W -> bf16 in B-fragment order; zero gcur ----
__global__ __launch_bounds__(256) void wconv(
    const float* __restrict__ W, u16* __restrict__ Wtg, u32* __restrict__ gcur) {
  int o = blockIdx.x * 256 + threadIdx.x;  // 0..8191
  int j = o & 7, col = (o >> 3) & 15, kq = (o >> 7) & 3, ks = (o >> 9) & 3,
      ct = (o >> 11) & 3;
  int k = ks * 32 + kq * 8 + j;
  int n = ct * 16 + col;
  Wtg[o] = f2bf(W[k * 64 + n]);
  if (o < MAXB) gcur[o] = 0;
}

// ---- K1: MFMA GEMM, 64 rows/block (4 waves x 16 rows), 64 cols ----
__global__ __launch_bounds__(256) void gemm_mfma(
    const float* __restrict__ h, const float* __restrict__ norm,
    const u16* __restrict__ Wtg, u16* __restrict__ scaledh, int N) {
  int lane = threadIdx.x & 63, wid = threadIdx.x >> 6;
  int col = lane & 15, kq = lane >> 4;

  s16x8 bfrag[4][4];
#pragma unroll
  for (int ct = 0; ct < 4; ++ct)
#pragma unroll
    for (int ks = 0; ks < 4; ++ks) {
      int f = ct * 16 + ks * 4 + kq;
      bfrag[ct][ks] =
          *reinterpret_cast<const s16x8*>(Wtg + ((size_t)(f * 16 + col) * 8));
    }

  int row0 = blockIdx.x * 64 + wid * 16;
  int myrow = row0 + col;
  int ldrow = myrow < N ? myrow : (N - 1);
  const float* __restrict__ hrow = h + (size_t)ldrow * 128 + kq * 8;

  f32x4 acc[4];
#pragma unroll
  for (int ct = 0; ct < 4; ++ct) acc[ct] = (f32x4){0.f, 0.f, 0.f, 0.f};

#pragma unroll
  for (int ks = 0; ks < 4; ++ks) {
    float4 x0 = *reinterpret_cast<const float4*>(hrow + ks * 32);
    float4 x1 = *reinterpret_cast<const float4*>(hrow + ks * 32 + 4);
    s16x8 a;
    a[0] = (short)f2bf(x0.x); a[1] = (short)f2bf(x0.y);
    a[2] = (short)f2bf(x0.z); a[3] = (short)f2bf(x0.w);
    a[4] = (short)f2bf(x1.x); a[5] = (short)f2bf(x1.y);
    a[6] = (short)f2bf(x1.z); a[7] = (short)f2bf(x1.w);
#pragma unroll
    for (int ct = 0; ct < 4; ++ct)
      acc[ct] =
          __builtin_amdgcn_mfma_f32_16x16x32_bf16(a, bfrag[ct][ks], acc[ct], 0, 0, 0);
  }

#pragma unroll
  for (int reg = 0; reg < 4; ++reg) {
    int node = row0 + kq * 4 + reg;
    if (node < N) {
      float nm = norm[node];
#pragma unroll
      for (int ct = 0; ct < 4; ++ct)
        scaledh[(size_t)node * 64 + ct * 16 + col] = f2bf(acc[ct][reg] * nm);
    }
  }
}

// ---- K2: bin edges by dst>>6 (1024 threads, 8 edges each) ----
__global__ __launch_bounds__(1024) void bin_edges(
    const int* __restrict__ src, const int* __restrict__ dst,
    u32* __restrict__ gcur, u32* __restrict__ bins, int E) {
  __shared__ u32 lhist[MAXB];
  __shared__ u32 lbase[MAXB];
  int t = threadIdx.x;
  for (int i = t; i < MAXB; i += 1024) lhist[i] = 0;
  __syncthreads();
  int e0 = blockIdx.x * EPB;
  int s[8], d[8];
  u32 r[8];
#pragma unroll
  for (int k = 0; k < 8; ++k) {
    int e = e0 + k * 1024 + t;  // coalesced
    bool ok = e < E;
    s[k] = ok ? src[e] : 0;
    d[k] = ok ? dst[e] : -1;
  }
#pragma unroll
  for (int k = 0; k < 8; ++k) {
    if (d[k] >= 0) r[k] = atomicAdd(&lhist[d[k] >> NB_LOG], 1u);  // ds_add_rtn
  }
  __syncthreads();
  for (int i = t; i < MAXB; i += 1024) {
    u32 c = lhist[i];
    lbase[i] = c ? atomicAdd(&gcur[i], c) : 0u;  // 1 global atomic/(block,bucket)
  }
  __syncthreads();
#pragma unroll
  for (int k = 0; k < 8; ++k) {
    if (d[k] >= 0) {
      int bk = d[k] >> NB_LOG;
      u32 p = lbase[bk] + r[k];
      if (p < CAP)
        bins[(size_t)bk * CAP + p] = ((u32)s[k] << NB_LOG) | (u32)(d[k] & (NPB - 1));
    }
  }
}

// ---- K3: per-bucket counting sort + group-owns-node gather-reduce ----
__global__ __launch_bounds__(RT) void bucket_reduce(
    const u16* __restrict__ scaledh, const u32* __restrict__ bins,
    const u32* __restrict__ gcur, const float* __restrict__ norm,
    const float4* __restrict__ bias4, float* __restrict__ out, int N) {
  __shared__ u32 hist[NPB];
  __shared__ u32 startp[NPB + 1];
  __shared__ u32 sorted[CAP];
  int bkt = blockIdx.x;
  int t = threadIdx.x, lane = t & 63, wid = t >> 6;
  int cnt = (int)gcur[bkt];
  if (cnt > CAP) cnt = CAP;
  if (t < NPB) hist[t] = 0;
  __syncthreads();

  const u32* __restrict__ my = bins + (size_t)bkt * CAP;
  u32 w[CAP / RT];
  u32 rk[CAP / RT];
#pragma unroll
  for (int k = 0; k < CAP / RT; ++k) {
    int e = k * RT + t;  // coalesced
    w[k] = (e < cnt) ? my[e] : 0xFFFFFFFFu;
  }
#pragma unroll
  for (int k = 0; k < CAP / RT; ++k) {
    if (w[k] != 0xFFFFFFFFu)
      rk[k] = atomicAdd(&hist[w[k] & (NPB - 1)], 1u);  // native int LDS atomic
  }
  __syncthreads();
  // wave-level exclusive scan of hist[0..63] (wave 0)
  if (t < NPB) {
    u32 v = hist[t];
    u32 inc = v;
#pragma unroll
    for (int m = 1; m < NPB; m <<= 1) {
      u32 x = __shfl_up(inc, m);
      if (t >= m) inc += x;
    }
    startp[t] = inc - v;
    if (t == NPB - 1) startp[NPB] = inc;
  }
  __syncthreads();
#pragma unroll
  for (int k = 0; k < CAP / RT; ++k) {
    if (w[k] != 0xFFFFFFFFu)
      sorted[startp[w[k] & (NPB - 1)] + rk[k]] = w[k] >> NB_LOG;
  }
  __syncthreads();

  // Gather: 16-lane group owns one node; A/B interleave -> 4 loads in flight.
  int grp = lane >> 4, c4 = lane & 15;
  float4 bl = bias4[c4];
  int base = bkt << NB_LOG;
  int cm1 = cnt - 1;  // clamp for speculative LDS reads (loop empty if cnt==0)
#pragma unroll
  for (int round = 0; round < 2; ++round) {
    int rA = (wid << 4) + (round << 3) + grp;  // wave strip: 16 nodes
    int rB = rA + 4;
    int jA = (int)startp[rA], eA = (int)startp[rA + 1];
    int jB = (int)startp[rB], eB = (int)startp[rB + 1];
    float4 aA = make_float4(0.f, 0.f, 0.f, 0.f);
    float4 aB = make_float4(0.f, 0.f, 0.f, 0.f);
    while (jA < eA || jB < eB) {
      int iA0 = (int)sorted[min(jA, cm1)];
      int iA1 = (int)sorted[min(jA + 1, cm1)];
      int iB0 = (int)sorted[min(jB, cm1)];
      int iB1 = (int)sorted[min(jB + 1, cm1)];
      uint2 vA0 = *reinterpret_cast<const uint2*>(scaledh + ((size_t)iA0 << 6) + (c4 << 2));
      uint2 vA1 = *reinterpret_cast<const uint2*>(scaledh + ((size_t)iA1 << 6) + (c4 << 2));
      uint2 vB0 = *reinterpret_cast<const uint2*>(scaledh + ((size_t)iB0 << 6) + (c4 << 2));
      uint2 vB1 = *reinterpret_cast<const uint2*>(scaledh + ((size_t)iB1 << 6) + (c4 << 2));
      uint2 z = make_uint2(0u, 0u);
      vA0 = (jA < eA) ? vA0 : z;
      vA1 = (jA + 1 < eA) ? vA1 : z;
      vB0 = (jB < eB) ? vB0 : z;
      vB1 = (jB + 1 < eB) ? vB1 : z;
      acc_bf16x4(aA, vA0);
      acc_bf16x4(aA, vA1);
      acc_bf16x4(aB, vB0);
      acc_bf16x4(aB, vB1);
      jA += 2;
      jB += 2;
    }
    int nodeA = base + rA, nodeB = base + rB;
    if (nodeA < N) {
      float nm = norm[nodeA];
      float4 o;
      o.x = fmaxf(fmaf(aA.x, nm, bl.x), 0.f);
      o.y = fmaxf(fmaf(aA.y, nm, bl.y), 0.f);
      o.z = fmaxf(fmaf(aA.z, nm, bl.z), 0.f);
      o.w = fmaxf(fmaf(aA.w, nm, bl.w), 0.f);
      *reinterpret_cast<float4*>(out + (size_t)nodeA * 64 + (c4 << 2)) = o;
    }
    if (nodeB < N) {
      float nm = norm[nodeB];
      float4 o;
      o.x = fmaxf(fmaf(aB.x, nm, bl.x), 0.f);
      o.y = fmaxf(fmaf(aB.y, nm, bl.y), 0.f);
      o.z = fmaxf(fmaf(aB.z, nm, bl.z), 0.f);
      o.w = fmaxf(fmaf(aB.w, nm, bl.w), 0.f);
      *reinterpret_cast<float4*>(out + (size_t)nodeB * 64 + (c4 << 2)) = o;
    }
  }
}

// ---- fallback (atomic scatter) ----
__global__ __launch_bounds__(256) void zero_out(float4* __restrict__ o4, size_t n4) {
  size_t tid = blockIdx.x * 256 + threadIdx.x;
  size_t stride = (size_t)gridDim.x * 256;
  for (size_t i = tid; i < n4; i += stride) o4[i] = make_float4(0.f, 0.f, 0.f, 0.f);
}

__global__ __launch_bounds__(256) void scatter_edges(
    const u16* __restrict__ scaledh, const int* __restrict__ src,
    const int* __restrict__ dst, float* __restrict__ agg, int E) {
  int lane = threadIdx.x & 63;
  int gwid = (blockIdx.x * 256 + threadIdx.x) >> 6;
  int nw = (gridDim.x * 256) >> 6;
  for (int e = gwid; e < E; e += nw) {
    int s = __builtin_amdgcn_readfirstlane(src[e]);
    int d = __builtin_amdgcn_readfirstlane(dst[e]);
    float v = bf2f(scaledh[(size_t)s * 64 + lane]);
    unsafeAtomicAdd(&agg[(size_t)d * 64 + lane], v);
  }
}

__global__ __launch_bounds__(256) void finalize(
    float4* __restrict__ out4, const float* __restrict__ norm,
    const float4* __restrict__ b4, int N) {
  size_t total4 = (size_t)N * 16;
  size_t tid = blockIdx.x * 256 + threadIdx.x;
  size_t stride = (size_t)gridDim.x * 256;
  for (size_t t = tid; t < total4; t += stride) {
    int i = (int)(t >> 4), q = (int)(t & 15);
    float4 v = out4[t];
    float nm = norm[i];
    float4 bb = b4[q];
    v.x = fmaxf(fmaf(v.x, nm, bb.x), 0.f);
    v.y = fmaxf(fmaf(v.y, nm, bb.y), 0.f);
    v.z = fmaxf(fmaf(v.z, nm, bb.z), 0.f);
    v.w = fmaxf(fmaf(v.w, nm, bb.w), 0.f);
    out4[t] = v;
  }
}

extern "C" void kernel_launch(void* const* d_in, const int* in_sizes, int n_in,
                              void* d_out, int out_size, void* d_ws, size_t ws_size,
                              hipStream_t stream) {
  const float* h    = (const float*)d_in[0];
  const float* norm = (const float*)d_in[1];
  const float* W    = (const float*)d_in[2];
  const float* b    = (const float*)d_in[3];
  const int*   src  = (const int*)d_in[4];
  const int*   dst  = (const int*)d_in[5];

  int N = in_sizes[1];
  int E = in_sizes[4];
  int nbuckets = (N + NPB - 1) >> NB_LOG;
  int nrb = (N + 63) >> 6;
  int nbinb = (E + EPB - 1) / EPB;

  char* ws = (char*)d_ws;
  size_t off = 0;
  u16* scaledh = (u16*)(ws + off); off += (((size_t)N * 64 * 2) + 255) & ~(size_t)255;
  u32* gcur    = (u32*)(ws + off); off += (MAXB * 4 + 255) & ~(size_t)255;
  u16* Wtg     = (u16*)(ws + off); off += (8192 * 2 + 255) & ~(size_t)255;
  u32* bins    = (u32*)(ws + off); off += (size_t)MAXB * CAP * 4;
  size_t needed = off;
  size_t needed_fb = (size_t)((char*)bins - ws);  // fallback: scaledh+gcur+Wtg only

  if (ws_size >= needed && nbuckets <= MAXB) {
    wconv<<<32, 256, 0, stream>>>(W, Wtg, gcur);
    gemm_mfma<<<nrb, 256, 0, stream>>>(h, norm, Wtg, scaledh, N);
    bin_edges<<<nbinb, 1024, 0, stream>>>(src, dst, gcur, bins, E);
    bucket_reduce<<<nbuckets, RT, 0, stream>>>(scaledh, bins, gcur, norm,
                                               (const float4*)b, (float*)d_out, N);
  } else if (ws_size >= needed_fb) {
    float* agg = (float*)d_out;
    wconv<<<32, 256, 0, stream>>>(W, Wtg, gcur);
    gemm_mfma<<<nrb, 256, 0, stream>>>(h, norm, Wtg, scaledh, N);
    zero_out<<<1024, 256, 0, stream>>>((float4*)agg, (size_t)N * 16);
    scatter_edges<<<2048, 256, 0, stream>>>(scaledh, src, dst, agg, E);
    finalize<<<1024, 256, 0, stream>>>((float4*)agg, norm, (const float4*)b, N);
  }
}

// Round 11
// 79.115 us; speedup vs baseline: 1.2799x; 1.0120x over previous
//
#include <hip/hip_runtime.h>

// GCN layer: out = relu( segment_sum( (h@W * norm)[src], dst ) * norm + b )
//
// Pipeline (de-fused):
//   K0 wconv        : Wtg = bf16(W) in MFMA B-fragment order; zero gcur[]  (~2us)
//   K1 gemm_mfma    : scaledh = bf16((h@W)*norm) via mfma_f32_16x16x32_bf16 (~15us)
//   K2 bin_edges    : bin edges by dst>>6, 1024 thr x 8 edges; LDS rank +
//                     1 global atomic per (block,bucket) reservation (~18us)
//   K3 bucket_reduce: per-bucket LDS counting sort + group-owns-node gather,
//                     4-edge unroll x A/B lists = 8 gathers in flight,
//                     fused *norm+b, relu float4 store (measured 40us -> target ~28)

typedef unsigned int u32;
typedef unsigned short u16;
typedef __attribute__((ext_vector_type(8))) short s16x8;   // 8 bf16 = 4 VGPR
typedef __attribute__((ext_vector_type(4))) float f32x4;

#define NB_LOG 6
#define NPB 64             // nodes per bucket
#define CAP 2048           // edge capacity per bucket (mean ~1024, sd ~32)
#define MAXB 2048          // max buckets supported (N <= 131072)
#define EPB 8192           // edges per bin block (1024 thr x 8)
#define RT 256             // bucket_reduce threads (4 waves)

__device__ __forceinline__ float bf2f(u16 v) {
  return __uint_as_float(((u32)v) << 16);
}
__device__ __forceinline__ u16 f2bf(float f) {
  u32 u = __float_as_uint(f);
  return (u16)((u + 0x7fffu + ((u >> 16) & 1u)) >> 16);  // RNE
}
__device__ __forceinline__ void acc_bf16x4(float4& a, uint2 v) {
  a.x += __uint_as_float(v.x << 16);
  a.y += __uint_as_float(v.x & 0xFFFF0000u);
  a.z += __uint_as_float(v.y << 16);
  a.w += __uint_as_float(v.y & 0xFFFF0000u);
}

// ---- K0: W -> bf16 in B-fragment order; zero gcur ----
__global__ __launch_bounds__(256) void wconv(
    const float* __restrict__ W, u16* __restrict__ Wtg, u32* __restrict__ gcur) {
  int o = blockIdx.x * 256 + threadIdx.x;  // 0..8191
  int j = o & 7, col = (o >> 3) & 15, kq = (o >> 7) & 3, ks = (o >> 9) & 3,
      ct = (o >> 11) & 3;
  int k = ks * 32 + kq * 8 + j;
  int n = ct * 16 + col;
  Wtg[o] = f2bf(W[k * 64 + n]);
  if (o < MAXB) gcur[o] = 0;
}

// ---- K1: MFMA GEMM, 64 rows/block (4 waves x 16 rows), 64 cols ----
__global__ __launch_bounds__(256) void gemm_mfma(
    const float* __restrict__ h, const float* __restrict__ norm,
    const u16* __restrict__ Wtg, u16* __restrict__ scaledh, int N) {
  int lane = threadIdx.x & 63, wid = threadIdx.x >> 6;
  int col = lane & 15, kq = lane >> 4;

  s16x8 bfrag[4][4];
#pragma unroll
  for (int ct = 0; ct < 4; ++ct)
#pragma unroll
    for (int ks = 0; ks < 4; ++ks) {
      int f = ct * 16 + ks * 4 + kq;
      bfrag[ct][ks] =
          *reinterpret_cast<const s16x8*>(Wtg + ((size_t)(f * 16 + col) * 8));
    }

  int row0 = blockIdx.x * 64 + wid * 16;
  int myrow = row0 + col;
  int ldrow = myrow < N ? myrow : (N - 1);
  const float* __restrict__ hrow = h + (size_t)ldrow * 128 + kq * 8;

  f32x4 acc[4];
#pragma unroll
  for (int ct = 0; ct < 4; ++ct) acc[ct] = (f32x4){0.f, 0.f, 0.f, 0.f};

#pragma unroll
  for (int ks = 0; ks < 4; ++ks) {
    float4 x0 = *reinterpret_cast<const float4*>(hrow + ks * 32);
    float4 x1 = *reinterpret_cast<const float4*>(hrow + ks * 32 + 4);
    s16x8 a;
    a[0] = (short)f2bf(x0.x); a[1] = (short)f2bf(x0.y);
    a[2] = (short)f2bf(x0.z); a[3] = (short)f2bf(x0.w);
    a[4] = (short)f2bf(x1.x); a[5] = (short)f2bf(x1.y);
    a[6] = (short)f2bf(x1.z); a[7] = (short)f2bf(x1.w);
#pragma unroll
    for (int ct = 0; ct < 4; ++ct)
      acc[ct] =
          __builtin_amdgcn_mfma_f32_16x16x32_bf16(a, bfrag[ct][ks], acc[ct], 0, 0, 0);
  }

#pragma unroll
  for (int reg = 0; reg < 4; ++reg) {
    int node = row0 + kq * 4 + reg;
    if (node < N) {
      float nm = norm[node];
#pragma unroll
      for (int ct = 0; ct < 4; ++ct)
        scaledh[(size_t)node * 64 + ct * 16 + col] = f2bf(acc[ct][reg] * nm);
    }
  }
}

// ---- K2: bin edges by dst>>6 (1024 threads, 8 edges each) ----
__global__ __launch_bounds__(1024) void bin_edges(
    const int* __restrict__ src, const int* __restrict__ dst,
    u32* __restrict__ gcur, u32* __restrict__ bins, int E) {
  __shared__ u32 lhist[MAXB];
  __shared__ u32 lbase[MAXB];
  int t = threadIdx.x;
  for (int i = t; i < MAXB; i += 1024) lhist[i] = 0;
  __syncthreads();
  int e0 = blockIdx.x * EPB;
  int s[8], d[8];
  u32 r[8];
#pragma unroll
  for (int k = 0; k < 8; ++k) {
    int e = e0 + k * 1024 + t;  // coalesced
    bool ok = e < E;
    s[k] = ok ? src[e] : 0;
    d[k] = ok ? dst[e] : -1;
  }
#pragma unroll
  for (int k = 0; k < 8; ++k) {
    if (d[k] >= 0) r[k] = atomicAdd(&lhist[d[k] >> NB_LOG], 1u);  // ds_add_rtn
  }
  __syncthreads();
  for (int i = t; i < MAXB; i += 1024) {
    u32 c = lhist[i];
    lbase[i] = c ? atomicAdd(&gcur[i], c) : 0u;  // 1 global atomic/(block,bucket)
  }
  __syncthreads();
#pragma unroll
  for (int k = 0; k < 8; ++k) {
    if (d[k] >= 0) {
      int bk = d[k] >> NB_LOG;
      u32 p = lbase[bk] + r[k];
      if (p < CAP)
        bins[(size_t)bk * CAP + p] = ((u32)s[k] << NB_LOG) | (u32)(d[k] & (NPB - 1));
    }
  }
}

// ---- K3: per-bucket counting sort + group-owns-node gather (8 loads in flight) ----
__global__ __launch_bounds__(RT) void bucket_reduce(
    const u16* __restrict__ scaledh, const u32* __restrict__ bins,
    const u32* __restrict__ gcur, const float* __restrict__ norm,
    const float4* __restrict__ bias4, float* __restrict__ out, int N) {
  __shared__ u32 hist[NPB];
  __shared__ u32 startp[NPB + 1];
  __shared__ u32 sorted[CAP];
  int bkt = blockIdx.x;
  int t = threadIdx.x, lane = t & 63, wid = t >> 6;
  int cnt = (int)gcur[bkt];
  if (cnt > CAP) cnt = CAP;
  if (t < NPB) hist[t] = 0;
  __syncthreads();

  const u32* __restrict__ my = bins + (size_t)bkt * CAP;
  u32 w[CAP / RT];
  u32 rk[CAP / RT];
#pragma unroll
  for (int k = 0; k < CAP / RT; ++k) {
    int e = k * RT + t;  // coalesced
    w[k] = (e < cnt) ? my[e] : 0xFFFFFFFFu;
  }
#pragma unroll
  for (int k = 0; k < CAP / RT; ++k) {
    if (w[k] != 0xFFFFFFFFu)
      rk[k] = atomicAdd(&hist[w[k] & (NPB - 1)], 1u);  // native int LDS atomic
  }
  __syncthreads();
  // wave-level exclusive scan of hist[0..63] (wave 0)
  if (t < NPB) {
    u32 v = hist[t];
    u32 inc = v;
#pragma unroll
    for (int m = 1; m < NPB; m <<= 1) {
      u32 x = __shfl_up(inc, m);
      if (t >= m) inc += x;
    }
    startp[t] = inc - v;
    if (t == NPB - 1) startp[NPB] = inc;
  }
  __syncthreads();
#pragma unroll
  for (int k = 0; k < CAP / RT; ++k) {
    if (w[k] != 0xFFFFFFFFu)
      sorted[startp[w[k] & (NPB - 1)] + rk[k]] = w[k] >> NB_LOG;
  }
  __syncthreads();

  // Gather: 16-lane group owns one node; 4-edge unroll x A/B lists
  // -> 8 independent uint2 gathers in flight per wave iteration.
  int grp = lane >> 4, c4 = lane & 15;
  float4 bl = bias4[c4];
  int base = bkt << NB_LOG;
  int cm1 = cnt - 1;  // clamp for speculative LDS reads (loop empty if cnt==0)
  const u16* __restrict__ sh = scaledh + (c4 << 2);
#pragma unroll
  for (int round = 0; round < 2; ++round) {
    int rA = (wid << 4) + (round << 3) + grp;  // wave strip: 16 nodes
    int rB = rA + 4;
    int jA = (int)startp[rA], eA = (int)startp[rA + 1];
    int jB = (int)startp[rB], eB = (int)startp[rB + 1];
    float4 aA0 = make_float4(0.f, 0.f, 0.f, 0.f);
    float4 aA1 = make_float4(0.f, 0.f, 0.f, 0.f);
    float4 aB0 = make_float4(0.f, 0.f, 0.f, 0.f);
    float4 aB1 = make_float4(0.f, 0.f, 0.f, 0.f);
    while (jA < eA || jB < eB) {
      int iA0 = (int)sorted[min(jA + 0, cm1)];
      int iA1 = (int)sorted[min(jA + 1, cm1)];
      int iA2 = (int)sorted[min(jA + 2, cm1)];
      int iA3 = (int)sorted[min(jA + 3, cm1)];
      int iB0 = (int)sorted[min(jB + 0, cm1)];
      int iB1 = (int)sorted[min(jB + 1, cm1)];
      int iB2 = (int)sorted[min(jB + 2, cm1)];
      int iB3 = (int)sorted[min(jB + 3, cm1)];
      uint2 vA0 = *reinterpret_cast<const uint2*>(sh + ((size_t)iA0 << 6));
      uint2 vA1 = *reinterpret_cast<const uint2*>(sh + ((size_t)iA1 << 6));
      uint2 vA2 = *reinterpret_cast<const uint2*>(sh + ((size_t)iA2 << 6));
      uint2 vA3 = *reinterpret_cast<const uint2*>(sh + ((size_t)iA3 << 6));
      uint2 vB0 = *reinterpret_cast<const uint2*>(sh + ((size_t)iB0 << 6));
      uint2 vB1 = *reinterpret_cast<const uint2*>(sh + ((size_t)iB1 << 6));
      uint2 vB2 = *reinterpret_cast<const uint2*>(sh + ((size_t)iB2 << 6));
      uint2 vB3 = *reinterpret_cast<const uint2*>(sh + ((size_t)iB3 << 6));
      uint2 z = make_uint2(0u, 0u);
      vA0 = (jA + 0 < eA) ? vA0 : z;
      vA1 = (jA + 1 < eA) ? vA1 : z;
      vA2 = (jA + 2 < eA) ? vA2 : z;
      vA3 = (jA + 3 < eA) ? vA3 : z;
      vB0 = (jB + 0 < eB) ? vB0 : z;
      vB1 = (jB + 1 < eB) ? vB1 : z;
      vB2 = (jB + 2 < eB) ? vB2 : z;
      vB3 = (jB + 3 < eB) ? vB3 : z;
      acc_bf16x4(aA0, vA0);
      acc_bf16x4(aA1, vA1);
      acc_bf16x4(aA0, vA2);
      acc_bf16x4(aA1, vA3);
      acc_bf16x4(aB0, vB0);
      acc_bf16x4(aB1, vB1);
      acc_bf16x4(aB0, vB2);
      acc_bf16x4(aB1, vB3);
      jA += 4;
      jB += 4;
    }
    int nodeA = base + rA, nodeB = base + rB;
    if (nodeA < N) {
      float nm = norm[nodeA];
      float4 o;
      o.x = fmaxf(fmaf(aA0.x + aA1.x, nm, bl.x), 0.f);
      o.y = fmaxf(fmaf(aA0.y + aA1.y, nm, bl.y), 0.f);
      o.z = fmaxf(fmaf(aA0.z + aA1.z, nm, bl.z), 0.f);
      o.w = fmaxf(fmaf(aA0.w + aA1.w, nm, bl.w), 0.f);
      *reinterpret_cast<float4*>(out + (size_t)nodeA * 64 + (c4 << 2)) = o;
    }
    if (nodeB < N) {
      float nm = norm[nodeB];
      float4 o;
      o.x = fmaxf(fmaf(aB0.x + aB1.x, nm, bl.x), 0.f);
      o.y = fmaxf(fmaf(aB0.y + aB1.y, nm, bl.y), 0.f);
      o.z = fmaxf(fmaf(aB0.z + aB1.z, nm, bl.z), 0.f);
      o.w = fmaxf(fmaf(aB0.w + aB1.w, nm, bl.w), 0.f);
      *reinterpret_cast<float4*>(out + (size_t)nodeB * 64 + (c4 << 2)) = o;
    }
  }
}

// ---- fallback (atomic scatter) ----
__global__ __launch_bounds__(256) void zero_out(float4* __restrict__ o4, size_t n4) {
  size_t tid = blockIdx.x * 256 + threadIdx.x;
  size_t stride = (size_t)gridDim.x * 256;
  for (size_t i = tid; i < n4; i += stride) o4[i] = make_float4(0.f, 0.f, 0.f, 0.f);
}

__global__ __launch_bounds__(256) void scatter_edges(
    const u16* __restrict__ scaledh, const int* __restrict__ src,
    const int* __restrict__ dst, float* __restrict__ agg, int E) {
  int lane = threadIdx.x & 63;
  int gwid = (blockIdx.x * 256 + threadIdx.x) >> 6;
  int nw = (gridDim.x * 256) >> 6;
  for (int e = gwid; e < E; e += nw) {
    int s = __builtin_amdgcn_readfirstlane(src[e]);
    int d = __builtin_amdgcn_readfirstlane(dst[e]);
    float v = bf2f(scaledh[(size_t)s * 64 + lane]);
    unsafeAtomicAdd(&agg[(size_t)d * 64 + lane], v);
  }
}

__global__ __launch_bounds__(256) void finalize(
    float4* __restrict__ out4, const float* __restrict__ norm,
    const float4* __restrict__ b4, int N) {
  size_t total4 = (size_t)N * 16;
  size_t tid = blockIdx.x * 256 + threadIdx.x;
  size_t stride = (size_t)gridDim.x * 256;
  for (size_t t = tid; t < total4; t += stride) {
    int i = (int)(t >> 4), q = (int)(t & 15);
    float4 v = out4[t];
    float nm = norm[i];
    float4 bb = b4[q];
    v.x = fmaxf(fmaf(v.x, nm, bb.x), 0.f);
    v.y = fmaxf(fmaf(v.y, nm, bb.y), 0.f);
    v.z = fmaxf(fmaf(v.z, nm, bb.z), 0.f);
    v.w = fmaxf(fmaf(v.w, nm, bb.w), 0.f);
    out4[t] = v;
  }
}

extern "C" void kernel_launch(void* const* d_in, const int* in_sizes, int n_in,
                              void* d_out, int out_size, void* d_ws, size_t ws_size,
                              hipStream_t stream) {
  const float* h    = (const float*)d_in[0];
  const float* norm = (const float*)d_in[1];
  const float* W    = (const float*)d_in[2];
  const float* b    = (const float*)d_in[3];
  const int*   src  = (const int*)d_in[4];
  const int*   dst  = (const int*)d_in[5];

  int N = in_sizes[1];
  int E = in_sizes[4];
  int nbuckets = (N + NPB - 1) >> NB_LOG;
  int nrb = (N + 63) >> 6;
  int nbinb = (E + EPB - 1) / EPB;

  char* ws = (char*)d_ws;
  size_t off = 0;
  u16* scaledh = (u16*)(ws + off); off += (((size_t)N * 64 * 2) + 255) & ~(size_t)255;
  u32* gcur    = (u32*)(ws + off); off += (MAXB * 4 + 255) & ~(size_t)255;
  u16* Wtg     = (u16*)(ws + off); off += (8192 * 2 + 255) & ~(size_t)255;
  u32* bins    = (u32*)(ws + off); off += (size_t)MAXB * CAP * 4;
  size_t needed = off;
  size_t needed_fb = (size_t)((char*)bins - ws);  // fallback: scaledh+gcur+Wtg only

  if (ws_size >= needed && nbuckets <= MAXB) {
    wconv<<<32, 256, 0, stream>>>(W, Wtg, gcur);
    gemm_mfma<<<nrb, 256, 0, stream>>>(h, norm, Wtg, scaledh, N);
    bin_edges<<<nbinb, 1024, 0, stream>>>(src, dst, gcur, bins, E);
    bucket_reduce<<<nbuckets, RT, 0, stream>>>(scaledh, bins, gcur, norm,
                                               (const float4*)b, (float*)d_out, N);
  } else if (ws_size >= needed_fb) {
    float* agg = (float*)d_out;
    wconv<<<32, 256, 0, stream>>>(W, Wtg, gcur);
    gemm_mfma<<<nrb, 256, 0, stream>>>(h, norm, Wtg, scaledh, N);
    zero_out<<<1024, 256, 0, stream>>>((float4*)agg, (size_t)N * 16);
    scatter_edges<<<2048, 256, 0, stream>>>(scaledh, src, dst, agg, E);
    finalize<<<1024, 256, 0, stream>>>((float4*)agg, norm, (const float4*)b, N);
  }
}

// Round 12
// 78.323 us; speedup vs baseline: 1.2929x; 1.0101x over previous
//
#include <hip/hip_runtime.h>

// GCN layer: out = relu( segment_sum( (h@W * norm)[src], dst ) * norm + b )
//
// Pipeline:
//   K0 wconv       : Wtg = bf16(W) in MFMA B-fragment order; zero gcur[] (~2us)
//   K1 bin_and_gemm: grid-fused, bin blocks FIRST (co-resident with gemm):
//                    blocks [0,nbinb)  : bin 8192 edges (1024 thr x 8) by dst>>6
//                                        — identical to measured-good bin_edges
//                    blocks [nbinb,..) : 256 rows/block (16 waves x 16 rows) MFMA
//                    The two paths stress disjoint resources (LDS-atomics/latency
//                    vs HBM/MFMA) -> overlap instead of 15+18 serial.
//   K2 bucket_reduce: per-bucket LDS counting sort + group-owns-node gather
//                    (8 uint2 gathers in flight), fused *norm+b, relu store.
//                    Pinned at ~40us by L3 random-line rate (8 XCD x 12.8MB @2.2TB/s).

typedef unsigned int u32;
typedef unsigned short u16;
typedef __attribute__((ext_vector_type(8))) short s16x8;   // 8 bf16 = 4 VGPR
typedef __attribute__((ext_vector_type(4))) float f32x4;

#define NB_LOG 6
#define NPB 64             // nodes per bucket
#define CAP 2048           // edge capacity per bucket (mean ~1024, sd ~32)
#define MAXB 2048          // max buckets supported (N <= 131072)
#define EPB 8192           // edges per bin block (1024 thr x 8)
#define RT 256             // bucket_reduce threads (4 waves)
#define GROWS 256          // gemm rows per fused block (16 waves x 16)

__device__ __forceinline__ float bf2f(u16 v) {
  return __uint_as_float(((u32)v) << 16);
}
__device__ __forceinline__ u16 f2bf(float f) {
  u32 u = __float_as_uint(f);
  return (u16)((u + 0x7fffu + ((u >> 16) & 1u)) >> 16);  // RNE
}
__device__ __forceinline__ void acc_bf16x4(float4& a, uint2 v) {
  a.x += __uint_as_float(v.x << 16);
  a.y += __uint_as_float(v.x & 0xFFFF0000u);
  a.z += __uint_as_float(v.y << 16);
  a.w += __uint_as_float(v.y & 0xFFFF0000u);
}

// ---- K0: W -> bf16 in B-fragment order; zero gcur ----
__global__ __launch_bounds__(256) void wconv(
    const float* __restrict__ W, u16* __restrict__ Wtg, u32* __restrict__ gcur) {
  int o = blockIdx.x * 256 + threadIdx.x;  // 0..8191
  int j = o & 7, col = (o >> 3) & 15, kq = (o >> 7) & 3, ks = (o >> 9) & 3,
      ct = (o >> 11) & 3;
  int k = ks * 32 + kq * 8 + j;
  int n = ct * 16 + col;
  Wtg[o] = f2bf(W[k * 64 + n]);
  if (o < MAXB) gcur[o] = 0;
}

// ---- K1: fused bin (first) + MFMA GEMM ----
__global__ __launch_bounds__(1024) void bin_and_gemm(
    const float* __restrict__ h, const float* __restrict__ norm,
    const u16* __restrict__ Wtg, u16* __restrict__ scaledh, int N, int nbinb,
    const int* __restrict__ src, const int* __restrict__ dst,
    u32* __restrict__ gcur, u32* __restrict__ bins, int E) {
  __shared__ u32 lhist[MAXB];  // 8 KB
  __shared__ u32 lbase[MAXB];  // 8 KB

  if ((int)blockIdx.x < nbinb) {
    // ---- bin path: identical to measured-good standalone bin_edges ----
    int t = threadIdx.x;
    for (int i = t; i < MAXB; i += 1024) lhist[i] = 0;
    __syncthreads();
    int e0 = blockIdx.x * EPB;
    int s[8], d[8];
    u32 r[8];
#pragma unroll
    for (int k = 0; k < 8; ++k) {
      int e = e0 + k * 1024 + t;  // coalesced
      bool ok = e < E;
      s[k] = ok ? src[e] : 0;
      d[k] = ok ? dst[e] : -1;
    }
#pragma unroll
    for (int k = 0; k < 8; ++k) {
      if (d[k] >= 0) r[k] = atomicAdd(&lhist[d[k] >> NB_LOG], 1u);  // ds_add_rtn
    }
    __syncthreads();
    for (int i = t; i < MAXB; i += 1024) {
      u32 c = lhist[i];
      lbase[i] = c ? atomicAdd(&gcur[i], c) : 0u;  // 1 global atomic/(block,bucket)
    }
    __syncthreads();
#pragma unroll
    for (int k = 0; k < 8; ++k) {
      if (d[k] >= 0) {
        int bk = d[k] >> NB_LOG;
        u32 p = lbase[bk] + r[k];
        if (p < CAP)
          bins[(size_t)bk * CAP + p] = ((u32)s[k] << NB_LOG) | (u32)(d[k] & (NPB - 1));
      }
    }
    return;
  }

  // ---- GEMM path: 256 rows/block (16 waves x 16 rows), 64 cols ----
  int lane = threadIdx.x & 63, wid = threadIdx.x >> 6;  // wid 0..15
  int col = lane & 15, kq = lane >> 4;

  s16x8 bfrag[4][4];
#pragma unroll
  for (int ct = 0; ct < 4; ++ct)
#pragma unroll
    for (int ks = 0; ks < 4; ++ks) {
      int f = ct * 16 + ks * 4 + kq;
      bfrag[ct][ks] =
          *reinterpret_cast<const s16x8*>(Wtg + ((size_t)(f * 16 + col) * 8));
    }

  int row0 = ((int)blockIdx.x - nbinb) * GROWS + wid * 16;
  int myrow = row0 + col;
  int ldrow = myrow < N ? myrow : (N - 1);
  const float* __restrict__ hrow = h + (size_t)ldrow * 128 + kq * 8;

  f32x4 acc[4];
#pragma unroll
  for (int ct = 0; ct < 4; ++ct) acc[ct] = (f32x4){0.f, 0.f, 0.f, 0.f};

#pragma unroll
  for (int ks = 0; ks < 4; ++ks) {
    float4 x0 = *reinterpret_cast<const float4*>(hrow + ks * 32);
    float4 x1 = *reinterpret_cast<const float4*>(hrow + ks * 32 + 4);
    s16x8 a;
    a[0] = (short)f2bf(x0.x); a[1] = (short)f2bf(x0.y);
    a[2] = (short)f2bf(x0.z); a[3] = (short)f2bf(x0.w);
    a[4] = (short)f2bf(x1.x); a[5] = (short)f2bf(x1.y);
    a[6] = (short)f2bf(x1.z); a[7] = (short)f2bf(x1.w);
#pragma unroll
    for (int ct = 0; ct < 4; ++ct)
      acc[ct] =
          __builtin_amdgcn_mfma_f32_16x16x32_bf16(a, bfrag[ct][ks], acc[ct], 0, 0, 0);
  }

#pragma unroll
  for (int reg = 0; reg < 4; ++reg) {
    int node = row0 + kq * 4 + reg;
    if (node < N) {
      float nm = norm[node];
#pragma unroll
      for (int ct = 0; ct < 4; ++ct)
        scaledh[(size_t)node * 64 + ct * 16 + col] = f2bf(acc[ct][reg] * nm);
    }
  }
}

// ---- K2: per-bucket counting sort + group-owns-node gather (8 loads in flight) ----
__global__ __launch_bounds__(RT) void bucket_reduce(
    const u16* __restrict__ scaledh, const u32* __restrict__ bins,
    const u32* __restrict__ gcur, const float* __restrict__ norm,
    const float4* __restrict__ bias4, float* __restrict__ out, int N) {
  __shared__ u32 hist[NPB];
  __shared__ u32 startp[NPB + 1];
  __shared__ u32 sorted[CAP];
  int bkt = blockIdx.x;
  int t = threadIdx.x, lane = t & 63, wid = t >> 6;
  int cnt = (int)gcur[bkt];
  if (cnt > CAP) cnt = CAP;
  if (t < NPB) hist[t] = 0;
  __syncthreads();

  const u32* __restrict__ my = bins + (size_t)bkt * CAP;
  u32 w[CAP / RT];
  u32 rk[CAP / RT];
#pragma unroll
  for (int k = 0; k < CAP / RT; ++k) {
    int e = k * RT + t;  // coalesced
    w[k] = (e < cnt) ? my[e] : 0xFFFFFFFFu;
  }
#pragma unroll
  for (int k = 0; k < CAP / RT; ++k) {
    if (w[k] != 0xFFFFFFFFu)
      rk[k] = atomicAdd(&hist[w[k] & (NPB - 1)], 1u);  // native int LDS atomic
  }
  __syncthreads();
  // wave-level exclusive scan of hist[0..63] (wave 0)
  if (t < NPB) {
    u32 v = hist[t];
    u32 inc = v;
#pragma unroll
    for (int m = 1; m < NPB; m <<= 1) {
      u32 x = __shfl_up(inc, m);
      if (t >= m) inc += x;
    }
    startp[t] = inc - v;
    if (t == NPB - 1) startp[NPB] = inc;
  }
  __syncthreads();
#pragma unroll
  for (int k = 0; k < CAP / RT; ++k) {
    if (w[k] != 0xFFFFFFFFu)
      sorted[startp[w[k] & (NPB - 1)] + rk[k]] = w[k] >> NB_LOG;
  }
  __syncthreads();

  // Gather: 16-lane group owns one node; 4-edge unroll x A/B lists
  // -> 8 independent uint2 gathers in flight per wave iteration.
  int grp = lane >> 4, c4 = lane & 15;
  float4 bl = bias4[c4];
  int base = bkt << NB_LOG;
  int cm1 = cnt - 1;  // clamp for speculative LDS reads (loop empty if cnt==0)
  const u16* __restrict__ sh = scaledh + (c4 << 2);
#pragma unroll
  for (int round = 0; round < 2; ++round) {
    int rA = (wid << 4) + (round << 3) + grp;  // wave strip: 16 nodes
    int rB = rA + 4;
    int jA = (int)startp[rA], eA = (int)startp[rA + 1];
    int jB = (int)startp[rB], eB = (int)startp[rB + 1];
    float4 aA0 = make_float4(0.f, 0.f, 0.f, 0.f);
    float4 aA1 = make_float4(0.f, 0.f, 0.f, 0.f);
    float4 aB0 = make_float4(0.f, 0.f, 0.f, 0.f);
    float4 aB1 = make_float4(0.f, 0.f, 0.f, 0.f);
    while (jA < eA || jB < eB) {
      int iA0 = (int)sorted[min(jA + 0, cm1)];
      int iA1 = (int)sorted[min(jA + 1, cm1)];
      int iA2 = (int)sorted[min(jA + 2, cm1)];
      int iA3 = (int)sorted[min(jA + 3, cm1)];
      int iB0 = (int)sorted[min(jB + 0, cm1)];
      int iB1 = (int)sorted[min(jB + 1, cm1)];
      int iB2 = (int)sorted[min(jB + 2, cm1)];
      int iB3 = (int)sorted[min(jB + 3, cm1)];
      uint2 vA0 = *reinterpret_cast<const uint2*>(sh + ((size_t)iA0 << 6));
      uint2 vA1 = *reinterpret_cast<const uint2*>(sh + ((size_t)iA1 << 6));
      uint2 vA2 = *reinterpret_cast<const uint2*>(sh + ((size_t)iA2 << 6));
      uint2 vA3 = *reinterpret_cast<const uint2*>(sh + ((size_t)iA3 << 6));
      uint2 vB0 = *reinterpret_cast<const uint2*>(sh + ((size_t)iB0 << 6));
      uint2 vB1 = *reinterpret_cast<const uint2*>(sh + ((size_t)iB1 << 6));
      uint2 vB2 = *reinterpret_cast<const uint2*>(sh + ((size_t)iB2 << 6));
      uint2 vB3 = *reinterpret_cast<const uint2*>(sh + ((size_t)iB3 << 6));
      uint2 z = make_uint2(0u, 0u);
      vA0 = (jA + 0 < eA) ? vA0 : z;
      vA1 = (jA + 1 < eA) ? vA1 : z;
      vA2 = (jA + 2 < eA) ? vA2 : z;
      vA3 = (jA + 3 < eA) ? vA3 : z;
      vB0 = (jB + 0 < eB) ? vB0 : z;
      vB1 = (jB + 1 < eB) ? vB1 : z;
      vB2 = (jB + 2 < eB) ? vB2 : z;
      vB3 = (jB + 3 < eB) ? vB3 : z;
      acc_bf16x4(aA0, vA0);
      acc_bf16x4(aA1, vA1);
      acc_bf16x4(aA0, vA2);
      acc_bf16x4(aA1, vA3);
      acc_bf16x4(aB0, vB0);
      acc_bf16x4(aB1, vB1);
      acc_bf16x4(aB0, vB2);
      acc_bf16x4(aB1, vB3);
      jA += 4;
      jB += 4;
    }
    int nodeA = base + rA, nodeB = base + rB;
    if (nodeA < N) {
      float nm = norm[nodeA];
      float4 o;
      o.x = fmaxf(fmaf(aA0.x + aA1.x, nm, bl.x), 0.f);
      o.y = fmaxf(fmaf(aA0.y + aA1.y, nm, bl.y), 0.f);
      o.z = fmaxf(fmaf(aA0.z + aA1.z, nm, bl.z), 0.f);
      o.w = fmaxf(fmaf(aA0.w + aA1.w, nm, bl.w), 0.f);
      *reinterpret_cast<float4*>(out + (size_t)nodeA * 64 + (c4 << 2)) = o;
    }
    if (nodeB < N) {
      float nm = norm[nodeB];
      float4 o;
      o.x = fmaxf(fmaf(aB0.x + aB1.x, nm, bl.x), 0.f);
      o.y = fmaxf(fmaf(aB0.y + aB1.y, nm, bl.y), 0.f);
      o.z = fmaxf(fmaf(aB0.z + aB1.z, nm, bl.z), 0.f);
      o.w = fmaxf(fmaf(aB0.w + aB1.w, nm, bl.w), 0.f);
      *reinterpret_cast<float4*>(out + (size_t)nodeB * 64 + (c4 << 2)) = o;
    }
  }
}

// ---- fallback (atomic scatter) ----
__global__ __launch_bounds__(256) void gemm_mfma_fb(
    const float* __restrict__ h, const float* __restrict__ norm,
    const u16* __restrict__ Wtg, u16* __restrict__ scaledh, int N) {
  int lane = threadIdx.x & 63, wid = threadIdx.x >> 6;
  int col = lane & 15, kq = lane >> 4;
  s16x8 bfrag[4][4];
#pragma unroll
  for (int ct = 0; ct < 4; ++ct)
#pragma unroll
    for (int ks = 0; ks < 4; ++ks) {
      int f = ct * 16 + ks * 4 + kq;
      bfrag[ct][ks] =
          *reinterpret_cast<const s16x8*>(Wtg + ((size_t)(f * 16 + col) * 8));
    }
  int row0 = blockIdx.x * 64 + wid * 16;
  int myrow = row0 + col;
  int ldrow = myrow < N ? myrow : (N - 1);
  const float* __restrict__ hrow = h + (size_t)ldrow * 128 + kq * 8;
  f32x4 acc[4];
#pragma unroll
  for (int ct = 0; ct < 4; ++ct) acc[ct] = (f32x4){0.f, 0.f, 0.f, 0.f};
#pragma unroll
  for (int ks = 0; ks < 4; ++ks) {
    float4 x0 = *reinterpret_cast<const float4*>(hrow + ks * 32);
    float4 x1 = *reinterpret_cast<const float4*>(hrow + ks * 32 + 4);
    s16x8 a;
    a[0] = (short)f2bf(x0.x); a[1] = (short)f2bf(x0.y);
    a[2] = (short)f2bf(x0.z); a[3] = (short)f2bf(x0.w);
    a[4] = (short)f2bf(x1.x); a[5] = (short)f2bf(x1.y);
    a[6] = (short)f2bf(x1.z); a[7] = (short)f2bf(x1.w);
#pragma unroll
    for (int ct = 0; ct < 4; ++ct)
      acc[ct] =
          __builtin_amdgcn_mfma_f32_16x16x32_bf16(a, bfrag[ct][ks], acc[ct], 0, 0, 0);
  }
#pragma unroll
  for (int reg = 0; reg < 4; ++reg) {
    int node = row0 + kq * 4 + reg;
    if (node < N) {
      float nm = norm[node];
#pragma unroll
      for (int ct = 0; ct < 4; ++ct)
        scaledh[(size_t)node * 64 + ct * 16 + col] = f2bf(acc[ct][reg] * nm);
    }
  }
}

__global__ __launch_bounds__(256) void zero_out(float4* __restrict__ o4, size_t n4) {
  size_t tid = blockIdx.x * 256 + threadIdx.x;
  size_t stride = (size_t)gridDim.x * 256;
  for (size_t i = tid; i < n4; i += stride) o4[i] = make_float4(0.f, 0.f, 0.f, 0.f);
}

__global__ __launch_bounds__(256) void scatter_edges(
    const u16* __restrict__ scaledh, const int* __restrict__ src,
    const int* __restrict__ dst, float* __restrict__ agg, int E) {
  int lane = threadIdx.x & 63;
  int gwid = (blockIdx.x * 256 + threadIdx.x) >> 6;
  int nw = (gridDim.x * 256) >> 6;
  for (int e = gwid; e < E; e += nw) {
    int s = __builtin_amdgcn_readfirstlane(src[e]);
    int d = __builtin_amdgcn_readfirstlane(dst[e]);
    float v = bf2f(scaledh[(size_t)s * 64 + lane]);
    unsafeAtomicAdd(&agg[(size_t)d * 64 + lane], v);
  }
}

__global__ __launch_bounds__(256) void finalize(
    float4* __restrict__ out4, const float* __restrict__ norm,
    const float4* __restrict__ b4, int N) {
  size_t total4 = (size_t)N * 16;
  size_t tid = blockIdx.x * 256 + threadIdx.x;
  size_t stride = (size_t)gridDim.x * 256;
  for (size_t t = tid; t < total4; t += stride) {
    int i = (int)(t >> 4), q = (int)(t & 15);
    float4 v = out4[t];
    float nm = norm[i];
    float4 bb = b4[q];
    v.x = fmaxf(fmaf(v.x, nm, bb.x), 0.f);
    v.y = fmaxf(fmaf(v.y, nm, bb.y), 0.f);
    v.z = fmaxf(fmaf(v.z, nm, bb.z), 0.f);
    v.w = fmaxf(fmaf(v.w, nm, bb.w), 0.f);
    out4[t] = v;
  }
}

extern "C" void kernel_launch(void* const* d_in, const int* in_sizes, int n_in,
                              void* d_out, int out_size, void* d_ws, size_t ws_size,
                              hipStream_t stream) {
  const float* h    = (const float*)d_in[0];
  const float* norm = (const float*)d_in[1];
  const float* W    = (const float*)d_in[2];
  const float* b    = (const float*)d_in[3];
  const int*   src  = (const int*)d_in[4];
  const int*   dst  = (const int*)d_in[5];

  int N = in_sizes[1];
  int E = in_sizes[4];
  int nbuckets = (N + NPB - 1) >> NB_LOG;
  int ngb = (N + GROWS - 1) / GROWS;          // fused gemm blocks (256 rows each)
  int nbinb = (E + EPB - 1) / EPB;

  char* ws = (char*)d_ws;
  size_t off = 0;
  u16* scaledh = (u16*)(ws + off); off += (((size_t)N * 64 * 2) + 255) & ~(size_t)255;
  u32* gcur    = (u32*)(ws + off); off += (MAXB * 4 + 255) & ~(size_t)255;
  u16* Wtg     = (u16*)(ws + off); off += (8192 * 2 + 255) & ~(size_t)255;
  u32* bins    = (u32*)(ws + off); off += (size_t)MAXB * CAP * 4;
  size_t needed = off;
  size_t needed_fb = (size_t)((char*)bins - ws);  // fallback: scaledh+gcur+Wtg only

  if (ws_size >= needed && nbuckets <= MAXB) {
    wconv<<<32, 256, 0, stream>>>(W, Wtg, gcur);
    bin_and_gemm<<<nbinb + ngb, 1024, 0, stream>>>(h, norm, Wtg, scaledh, N, nbinb,
                                                   src, dst, gcur, bins, E);
    bucket_reduce<<<nbuckets, RT, 0, stream>>>(scaledh, bins, gcur, norm,
                                               (const float4*)b, (float*)d_out, N);
  } else if (ws_size >= needed_fb) {
    float* agg = (float*)d_out;
    wconv<<<32, 256, 0, stream>>>(W, Wtg, gcur);
    gemm_mfma_fb<<<(N + 63) >> 6, 256, 0, stream>>>(h, norm, Wtg, scaledh, N);
    zero_out<<<1024, 256, 0, stream>>>((float4*)agg, (size_t)N * 16);
    scatter_edges<<<2048, 256, 0, stream>>>(scaledh, src, dst, agg, E);
    finalize<<<1024, 256, 0, stream>>>((float4*)agg, norm, (const float4*)b, N);
  }
}